// Round 11
// baseline (442.521 us; speedup 1.0000x reference)
//
#include <hip/hip_runtime.h>
#include <stdint.h>

typedef __attribute__((ext_vector_type(8))) short s16x8;
typedef __attribute__((ext_vector_type(4))) float f32x4;

__device__ __forceinline__ ushort f2bf(float x) {
  union { float f; uint32_t u; } v; v.f = x;
  uint32_t r = v.u + 0x7FFFu + ((v.u >> 16) & 1u);
  return (ushort)(r >> 16);
}
__device__ __forceinline__ float bf2f(ushort u) {
  union { uint32_t u; float f; } v; v.u = ((uint32_t)u) << 16; return v.f;
}

// Barrier that waits only LDS ops (lgkmcnt); global stores stay in flight.
__device__ __forceinline__ void barrier_lds_only() {
  asm volatile("s_waitcnt lgkmcnt(0)" ::: "memory");
  __builtin_amdgcn_s_barrier();
}

// ---------------------------------------------------------------------------
// Weight prep, 10 slots of transposed bf16 [col][k] + f32 bias.
//  0: kw0 raw  1: kw1 raw  2: vw0 raw  3: vw1 raw          (P projections)
//  4: qw0@BD(att0^T)  5: qw1@BD(att1^T)  6: qw0@BD(att2^T) (q-tilde weights)
//  7: BD(msg0)@aw0    8: BD(msg1)@aw1    9: BD(msg2)@aw0   (folded output W)
// Identities: score=q·(k@att)=(q@att^T)·k ;  (aggΣw·v)@msg@aw = agg@(msg@aw)
// ---------------------------------------------------------------------------
__global__ __launch_bounds__(256) void prep_weights(
    const float* __restrict__ kw, const float* __restrict__ kb,
    const float* __restrict__ qw, const float* __restrict__ qb,
    const float* __restrict__ vw, const float* __restrict__ vb,
    const float* __restrict__ aw, const float* __restrict__ ab,
    const float* __restrict__ rel_att, const float* __restrict__ rel_msg,
    ushort* __restrict__ WT, float* __restrict__ BIAS)
{
  int slot = blockIdx.x, tid = threadIdx.x;
  const float* W; const float* b; const float* rel = nullptr; int mode;
  switch (slot) {
    case 0: W = kw;         b = kb;       mode = 0; break;
    case 1: W = kw + 16384; b = kb + 128; mode = 0; break;
    case 2: W = vw;         b = vb;       mode = 0; break;
    case 3: W = vw + 16384; b = vb + 128; mode = 0; break;
    case 4: W = qw;         b = qb;       rel = rel_att;        mode = 1; break;
    case 5: W = qw + 16384; b = qb + 128; rel = rel_att + 2048; mode = 1; break;
    case 6: W = qw;         b = qb;       rel = rel_att + 4096; mode = 1; break;
    case 7: W = aw;         b = ab;       rel = rel_msg;        mode = 2; break;
    case 8: W = aw + 16384; b = ab + 128; rel = rel_msg + 2048; mode = 2; break;
    default: W = aw;        b = ab;       rel = rel_msg + 4096; mode = 2; break;
  }
  ushort* out = WT + slot * 16384;
  for (int e = tid; e < 16384; e += 256) {
    int c = e >> 7, k = e & 127;
    float val;
    if (mode == 0) {
      val = W[k*128 + c];
    } else if (mode == 1) {           // qt: col c=(h,i): sum_j qw[:,h,j]*att[h,i,j]
      int h = c >> 4, cc = c & 15;
      float s = 0.f;
      #pragma unroll
      for (int j = 0; j < 16; j++) s += W[k*128 + h*16 + j] * rel[h*256 + cc*16 + j];
      val = s;
    } else {                          // F: row k=(h,i): sum_j msg[h,i,j]*aw[h*16+j, c]
      int hr = k >> 4, ir = k & 15;
      float s = 0.f;
      #pragma unroll
      for (int j = 0; j < 16; j++) s += rel[hr*256 + ir*16 + j] * W[(hr*16 + j)*128 + c];
      val = s;
    }
    out[c*128 + k] = f2bf(val);       // transposed [col][k]
  }
  if (tid < 128) {
    int c = tid; float val;
    if (mode == 1) {
      int h = c >> 4, cc = c & 15;
      float s = 0.f;
      #pragma unroll
      for (int j = 0; j < 16; j++) s += b[h*16 + j] * rel[h*256 + cc*16 + j];
      val = s;
    } else {
      val = b[c];                     // raw k/v bias, or ab for F slots
    }
    BIAS[slot*128 + c] = val;
  }
}

// ---------------------------------------------------------------------------
// Projection GEMM: only 4 raw slots now (k0,v0 from h0; k1,v1 from h1).
// Double-buffered LDS pipeline, nt copy-out (2 store streams per block).
//   blockIdx.y = 0 : A = h0, slots {0,2} (map 0x20)
//   blockIdx.y = 1 : A = h1, slots {1,3} (map 0x31)
// ---------------------------------------------------------------------------
__global__ __launch_bounds__(256) void proj_fused(
    const float* __restrict__ h0, const float* __restrict__ h1,
    const ushort* __restrict__ WT, const float* __restrict__ BIAS,
    ushort* __restrict__ P, int N)
{
  __shared__ ushort ALDS0[64 * 132];
  __shared__ ushort ALDS1[64 * 132];

  int src_t = blockIdx.y;
  const float* A = src_t ? h1 : h0;
  unsigned smap = src_t ? 0x31u : 0x20u;
  const int nslots = 2;

  int tid = threadIdx.x;
  int lane = tid & 63;
  int wave = tid >> 6;
  int lr = lane & 15, lh = lane >> 4;
  int colbase = (wave & 1) * 64;
  int rowhalf = wave >> 1;

  int base = blockIdx.x * 64;
  if (base >= N) return;

  s16x8 af[2][4];
  #pragma unroll
  for (int rg = 0; rg < 2; rg++) {
    int arow = base + rowhalf*32 + rg*16 + lr;
    if (arow >= N) arow = N - 1;
    #pragma unroll
    for (int ks = 0; ks < 4; ks++) {
      const float* ap = A + (size_t)arow*128 + ks*32 + lh*8;
      f32x4 x0 = *(const f32x4*)ap;
      f32x4 x1 = *(const f32x4*)(ap + 4);
      s16x8 v;
      #pragma unroll
      for (int j = 0; j < 4; j++) { v[j] = (short)f2bf(x0[j]); v[4+j] = (short)f2bf(x1[j]); }
      af[rg][ks] = v;
    }
  }

  auto compute_slot = [&](int g, ushort* L) {
    const ushort* Bt = WT + g * 16384;
    const float* bias = BIAS + g * 128;
    #pragma unroll
    for (int ct = 0; ct < 4; ct++) {
      int col = colbase + ct*16 + lr;
      s16x8 bfr[4];
      #pragma unroll
      for (int ks = 0; ks < 4; ks++)
        bfr[ks] = *(const s16x8*)(Bt + col*128 + ks*32 + lh*8);
      float bb = bias[col];
      #pragma unroll
      for (int rg = 0; rg < 2; rg++) {
        f32x4 acc = { bb, bb, bb, bb };
        #pragma unroll
        for (int ks = 0; ks < 4; ks++)
          acc = __builtin_amdgcn_mfma_f32_16x16x32_bf16(af[rg][ks], bfr[ks], acc, 0, 0, 0);
        int rl0 = rowhalf*32 + rg*16 + lh*4;
        #pragma unroll
        for (int i = 0; i < 4; i++)
          L[(rl0 + i) * 132 + col] = f2bf(acc[i]);
      }
    }
  };

  auto copyout = [&](int g, const ushort* L) {
    ushort* C = P + (size_t)g * N * 128;
    #pragma unroll
    for (int j = 0; j < 4; j++) {
      int idx = j * 256 + tid;
      int row = idx >> 4, ch = idx & 15;
      int gr = base + row;
      if (gr < N)
        __builtin_nontemporal_store(
            *(const s16x8*)(L + row * 132 + ch * 8),
            (s16x8*)(C + (size_t)gr * 128 + ch * 8));
    }
  };

  int prev = smap & 15;
  compute_slot(prev, ALDS0);
  barrier_lds_only();
  for (int si = 1; si < nslots; si++) {
    int g = (smap >> (si * 4)) & 15;
    copyout(prev, ALDS0);
    compute_slot(g, ALDS1);
    barrier_lds_only();
    prev = g;
  }
  copyout(prev, ALDS1);
}

// ---------------------------------------------------------------------------
// CSR build (unchanged)
// ---------------------------------------------------------------------------
__global__ void count_edges(const int* __restrict__ d0, const int* __restrict__ d1,
                            const int* __restrict__ d2, int* __restrict__ counts,
                            int E, int N)
{
  int idx = blockIdx.x * 256 + threadIdx.x;
  if (idx >= 3 * E) return;
  int r = idx / E, e = idx - r * E;
  const int* D = (r == 0) ? d0 : (r == 1) ? d1 : d2;
  atomicAdd(counts + r * N + D[e], 1);
}

#define SCAN_CHUNK 2048
#define MAXC 1024

__global__ __launch_bounds__(256) void scan_partial(
    const int* __restrict__ counts, int* __restrict__ offsets,
    int* __restrict__ bsum, int N)
{
  int r = blockIdx.y, c = blockIdx.x, tid = threadIdx.x;
  const int* cnt = counts + (size_t)r * N;
  int* o = offsets + (size_t)r * (N + 1);
  int idx0 = c * SCAN_CHUNK + tid * 8;
  int p[8]; int run = 0;
  #pragma unroll
  for (int j = 0; j < 8; j++) {
    int v = (idx0 + j < N) ? cnt[idx0 + j] : 0;
    run += v; p[j] = run;
  }
  int lane = tid & 63, wid = tid >> 6;
  int x = run;
  #pragma unroll
  for (int off = 1; off < 64; off <<= 1) {
    int t = __shfl_up(x, off, 64);
    if (lane >= off) x += t;
  }
  __shared__ int wsum[4];
  if (lane == 63) wsum[wid] = x;
  __syncthreads();
  int woff = 0;
  for (int wph = 0; wph < wid; wph++) woff += wsum[wph];
  int texcl = woff + x - run;
  #pragma unroll
  for (int j = 0; j < 8; j++)
    if (idx0 + j < N) o[idx0 + j + 1] = texcl + p[j];
  if (tid == 255) bsum[r * MAXC + c] = woff + x;
}

__global__ void scan_bsums(int* __restrict__ bsum, int nchunks)
{
  int r = blockIdx.x, lane = threadIdx.x;
  int carry = 0;
  for (int base = 0; base < nchunks; base += 64) {
    int i = base + lane;
    int v0 = (i < nchunks) ? bsum[r * MAXC + i] : 0;
    int x = v0;
    #pragma unroll
    for (int off = 1; off < 64; off <<= 1) {
      int t = __shfl_up(x, off, 64);
      if (lane >= off) x += t;
    }
    if (i < nchunks) bsum[r * MAXC + i] = carry + x - v0;
    carry += __shfl(x, 63, 64);
  }
}

__global__ __launch_bounds__(256) void scan_add(
    int* __restrict__ offsets, const int* __restrict__ bsum, int N)
{
  int r = blockIdx.y, c = blockIdx.x, tid = threadIdx.x;
  int* o = offsets + (size_t)r * (N + 1);
  if (c == 0 && tid == 0) o[0] = 0;
  int add = bsum[r * MAXC + c];
  if (add == 0) return;
  int idx0 = c * SCAN_CHUNK + tid * 8;
  #pragma unroll
  for (int j = 0; j < 8; j++) {
    int i = idx0 + j;
    if (i < N) o[i + 1] += add;
  }
}

__global__ void scatter_edges(const int* __restrict__ d0, const int* __restrict__ d1,
                              const int* __restrict__ d2,
                              const int* __restrict__ offsets, int* __restrict__ cursor,
                              int* __restrict__ elist, int E, int N)
{
  int idx = blockIdx.x * 256 + threadIdx.x;
  if (idx >= 3 * E) return;
  int r = idx / E, e = idx - r * E;
  const int* D = (r == 0) ? d0 : (r == 1) ? d1 : d2;
  int dst = D[e];
  int pos = offsets[r * (N + 1) + dst] + atomicAdd(cursor + r * N + dst, 1);
  elist[r * E + pos] = e;
}

// ---------------------------------------------------------------------------
// Fully fused attention + output, with dst-side q-tilde and folded msg@aw.
// Phase 0: in-block MFMA computes qt_r = h[dst tile] @ WTq_r (+bias) -> LDS.
// Phase 1: per (dst,h): single pass over CSR edges: gather raw k[src], score =
//          qt·k (no max-sub; |score|<~8, f32-safe), w=exp, gather raw v[src],
//          accumulate; normalize -> raw per-relation aggregates in LDS.
// Phase 2: out = (1/nrel)(A_r0@F_r0 [+ A_r2@F_r2]) + ab, skip-mix, nt store.
// Block = 256 threads = 32 dst x 8 heads.
// ---------------------------------------------------------------------------
__global__ __launch_bounds__(256) void agg_final(
    const int* __restrict__ elistA, const int* __restrict__ offsA,
    const int* __restrict__ SA,
    const ushort* __restrict__ KA, const ushort* __restrict__ VA,
    const int* __restrict__ elistB, const int* __restrict__ offsB,
    const int* __restrict__ SB,
    const ushort* __restrict__ KB, const ushort* __restrict__ VB,
    int nrel, int rA, int rB,
    int qslotA, int qslotB, int fslotA, int fslotB,
    const ushort* __restrict__ WT, const float* __restrict__ BIAS,
    const float* __restrict__ H, const float* __restrict__ rel_pri,
    const float* __restrict__ skip, int t,
    float* __restrict__ outT, int N)
{
  __shared__ ushort T0[32 * 132];
  __shared__ ushort T1[32 * 132];

  int tid = threadIdx.x;
  int lane = tid & 63, wv = tid >> 6;
  int lr = lane & 15, lh = lane >> 4;
  int rowhalf = wv & 1, colhalf = wv >> 1;
  int base = blockIdx.x * 32;

  // ---- phase 0: qt tiles via MFMA ----
  s16x8 af[4];
  {
    int arow = base + rowhalf*16 + lr;
    if (arow >= N) arow = N - 1;
    #pragma unroll
    for (int ks = 0; ks < 4; ks++) {
      const float* ap = H + (size_t)arow*128 + ks*32 + lh*8;
      f32x4 x0 = *(const f32x4*)ap;
      f32x4 x1 = *(const f32x4*)(ap + 4);
      s16x8 v;
      #pragma unroll
      for (int j = 0; j < 4; j++) { v[j] = (short)f2bf(x0[j]); v[4+j] = (short)f2bf(x1[j]); }
      af[ks] = v;
    }
  }
  {
    const ushort* Bt = WT + qslotA * 16384;
    const float* bq = BIAS + qslotA * 128;
    #pragma unroll
    for (int ct = 0; ct < 4; ct++) {
      int col = colhalf*64 + ct*16 + lr;
      s16x8 bfr[4];
      #pragma unroll
      for (int ks = 0; ks < 4; ks++)
        bfr[ks] = *(const s16x8*)(Bt + col*128 + ks*32 + lh*8);
      float bb = bq[col];
      f32x4 acc = { bb, bb, bb, bb };
      #pragma unroll
      for (int ks = 0; ks < 4; ks++)
        acc = __builtin_amdgcn_mfma_f32_16x16x32_bf16(af[ks], bfr[ks], acc, 0, 0, 0);
      int r0l = rowhalf*16 + lh*4;
      #pragma unroll
      for (int i = 0; i < 4; i++) T0[(r0l + i)*132 + col] = f2bf(acc[i]);
    }
  }
  if (nrel == 2) {
    const ushort* Bt = WT + qslotB * 16384;
    const float* bq = BIAS + qslotB * 128;
    #pragma unroll
    for (int ct = 0; ct < 4; ct++) {
      int col = colhalf*64 + ct*16 + lr;
      s16x8 bfr[4];
      #pragma unroll
      for (int ks = 0; ks < 4; ks++)
        bfr[ks] = *(const s16x8*)(Bt + col*128 + ks*32 + lh*8);
      float bb = bq[col];
      f32x4 acc = { bb, bb, bb, bb };
      #pragma unroll
      for (int ks = 0; ks < 4; ks++)
        acc = __builtin_amdgcn_mfma_f32_16x16x32_bf16(af[ks], bfr[ks], acc, 0, 0, 0);
      int r0l = rowhalf*16 + lh*4;
      #pragma unroll
      for (int i = 0; i < 4; i++) T1[(r0l + i)*132 + col] = f2bf(acc[i]);
    }
  }
  __syncthreads();

  // ---- phase 1: per-(dst,h) edge aggregation ----
  int dstl = tid >> 3, h = tid & 7;
  int dst = base + dstl;
  bool valid = dst < N;

  float qfA[16], qfB[16];
  {
    const ushort* qr = T0 + dstl*132 + h*16;
    #pragma unroll
    for (int j = 0; j < 16; j++) qfA[j] = bf2f(qr[j]);
  }
  if (nrel == 2) {
    const ushort* qr = T1 + dstl*132 + h*16;
    #pragma unroll
    for (int j = 0; j < 16; j++) qfB[j] = bf2f(qr[j]);
  }
  __syncthreads();

  float accA[16], accB[16];
  {
    float pr = rel_pri[rA*8 + h] * 0.25f;
    int b0 = valid ? offsA[dst] : 0, b1 = valid ? offsA[dst + 1] : 0;
    float sum = 0.f;
    #pragma unroll
    for (int j = 0; j < 16; j++) accA[j] = 0.f;
    for (int i = b0; i < b1; i++) {
      int e = elistA[i];
      int s = SA[e];
      const ushort* kr = KA + (size_t)s*128 + h*16;
      s16x8 k0 = *(const s16x8*)kr;
      s16x8 k1 = *(const s16x8*)(kr + 8);
      float sc = 0.f;
      #pragma unroll
      for (int j = 0; j < 8; j++)
        sc += qfA[j]*bf2f((ushort)k0[j]) + qfA[8+j]*bf2f((ushort)k1[j]);
      float w = __expf(sc * pr);
      const ushort* vr = VA + (size_t)s*128 + h*16;
      s16x8 v0 = *(const s16x8*)vr;
      s16x8 v1 = *(const s16x8*)(vr + 8);
      #pragma unroll
      for (int j = 0; j < 8; j++) {
        accA[j]   += w * bf2f((ushort)v0[j]);
        accA[8+j] += w * bf2f((ushort)v1[j]);
      }
      sum += w;
    }
    float inv = (b1 > b0) ? 1.0f / sum : 0.f;
    #pragma unroll
    for (int j = 0; j < 16; j++) accA[j] *= inv;
  }
  if (nrel == 2) {
    float pr = rel_pri[rB*8 + h] * 0.25f;
    int b0 = valid ? offsB[dst] : 0, b1 = valid ? offsB[dst + 1] : 0;
    float sum = 0.f;
    #pragma unroll
    for (int j = 0; j < 16; j++) accB[j] = 0.f;
    for (int i = b0; i < b1; i++) {
      int e = elistB[i];
      int s = SB[e];
      const ushort* kr = KB + (size_t)s*128 + h*16;
      s16x8 k0 = *(const s16x8*)kr;
      s16x8 k1 = *(const s16x8*)(kr + 8);
      float sc = 0.f;
      #pragma unroll
      for (int j = 0; j < 8; j++)
        sc += qfB[j]*bf2f((ushort)k0[j]) + qfB[8+j]*bf2f((ushort)k1[j]);
      float w = __expf(sc * pr);
      const ushort* vr = VB + (size_t)s*128 + h*16;
      s16x8 v0 = *(const s16x8*)vr;
      s16x8 v1 = *(const s16x8*)(vr + 8);
      #pragma unroll
      for (int j = 0; j < 8; j++) {
        accB[j]   += w * bf2f((ushort)v0[j]);
        accB[8+j] += w * bf2f((ushort)v1[j]);
      }
      sum += w;
    }
    float inv = (b1 > b0) ? 1.0f / sum : 0.f;
    #pragma unroll
    for (int j = 0; j < 16; j++) accB[j] *= inv;
  }
  {
    ushort* a0 = T0 + dstl*132 + h*16;
    #pragma unroll
    for (int j = 0; j < 16; j++) a0[j] = f2bf(accA[j]);
    if (nrel == 2) {
      ushort* a1 = T1 + dstl*132 + h*16;
      #pragma unroll
      for (int j = 0; j < 16; j++) a1[j] = f2bf(accB[j]);
    }
  }
  __syncthreads();

  // ---- phase 2: output GEMM with folded F_r, mean, +ab, skip-mix ----
  const float* bias = BIAS + fslotA * 128;   // ab[t]
  float alpha = 1.0f / (1.0f + __expf(-skip[t]));
  float beta = 1.0f - alpha;
  float rscale = (nrel == 2) ? 0.5f : 1.0f;

  s16x8 afA[4], afB[4];
  int arow_l = rowhalf*16 + lr;
  #pragma unroll
  for (int ks = 0; ks < 4; ks++)
    afA[ks] = *(const s16x8*)(T0 + arow_l*132 + ks*32 + lh*8);
  if (nrel == 2) {
    #pragma unroll
    for (int ks = 0; ks < 4; ks++)
      afB[ks] = *(const s16x8*)(T1 + arow_l*132 + ks*32 + lh*8);
  }

  #pragma unroll
  for (int ct = 0; ct < 4; ct++) {
    int col = colhalf*64 + ct*16 + lr;
    s16x8 bfrA[4];
    const ushort* BtA = WT + fslotA * 16384;
    #pragma unroll
    for (int ks = 0; ks < 4; ks++)
      bfrA[ks] = *(const s16x8*)(BtA + col*128 + ks*32 + lh*8);
    f32x4 acc = { 0.f, 0.f, 0.f, 0.f };
    #pragma unroll
    for (int ks = 0; ks < 4; ks++)
      acc = __builtin_amdgcn_mfma_f32_16x16x32_bf16(afA[ks], bfrA[ks], acc, 0, 0, 0);
    if (nrel == 2) {
      const ushort* BtB = WT + fslotB * 16384;
      s16x8 bfrB[4];
      #pragma unroll
      for (int ks = 0; ks < 4; ks++)
        bfrB[ks] = *(const s16x8*)(BtB + col*128 + ks*32 + lh*8);
      #pragma unroll
      for (int ks = 0; ks < 4; ks++)
        acc = __builtin_amdgcn_mfma_f32_16x16x32_bf16(afB[ks], bfrB[ks], acc, 0, 0, 0);
    }
    float bb = bias[col];
    int r0l = rowhalf*16 + lh*4;
    #pragma unroll
    for (int i = 0; i < 4; i++) {
      int g = base + r0l + i;
      if (g < N) {
        size_t off = (size_t)g*128 + col;
        __builtin_nontemporal_store((acc[i]*rscale + bb)*alpha + H[off]*beta,
                                    &outT[off]);
      }
    }
  }
}

// ---------------------------------------------------------------------------
extern "C" void kernel_launch(void* const* d_in, const int* in_sizes, int n_in,
                              void* d_out, int out_size, void* d_ws, size_t ws_size,
                              hipStream_t stream)
{
  const float* h0      = (const float*)d_in[0];
  const float* h1      = (const float*)d_in[1];
  const float* kw      = (const float*)d_in[2];
  const float* kb      = (const float*)d_in[3];
  const float* qw      = (const float*)d_in[4];
  const float* qb      = (const float*)d_in[5];
  const float* vw      = (const float*)d_in[6];
  const float* vb      = (const float*)d_in[7];
  const float* aw      = (const float*)d_in[8];
  const float* ab      = (const float*)d_in[9];
  const float* rel_att = (const float*)d_in[10];
  const float* rel_msg = (const float*)d_in[11];
  const float* rel_pri = (const float*)d_in[12];
  const float* skip    = (const float*)d_in[13];
  const int* s0 = (const int*)d_in[14];
  const int* d0 = (const int*)d_in[15];
  const int* s1 = (const int*)d_in[16];
  const int* d1 = (const int*)d_in[17];
  const int* s2 = (const int*)d_in[18];
  const int* d2 = (const int*)d_in[19];

  int N = in_sizes[0] / 128;
  int E = in_sizes[14];

  char* w = (char*)d_ws;
  size_t o = 0;
  auto alloc = [&](size_t bytes) { size_t cur = o; o += (bytes + 255) / 256 * 256; return cur; };
  ushort* WT   = (ushort*)(w + alloc((size_t)10 * 16384 * 2));
  float*  BIAS = (float*) (w + alloc((size_t)10 * 128 * 4));
  ushort* P    = (ushort*)(w + alloc((size_t)4 * N * 128 * 2));
  int* counts  = (int*)   (w + alloc((size_t)3 * N * 4));
  int* cursor  = (int*)   (w + alloc((size_t)3 * N * 4));
  int* offs    = (int*)   (w + alloc((size_t)3 * (N + 1) * 4));
  int* elist   = (int*)   (w + alloc((size_t)3 * E * 4));
  int* bsum    = (int*)   (w + alloc((size_t)3 * MAXC * 4));
  (void)ws_size; (void)n_in; (void)out_size;

  hipMemsetAsync(counts, 0, (size_t)3 * N * 4, stream);
  hipMemsetAsync(cursor, 0, (size_t)3 * N * 4, stream);

  prep_weights<<<10, 256, 0, stream>>>(kw, kb, qw, qb, vw, vb, aw, ab,
                                       rel_att, rel_msg, WT, BIAS);

  proj_fused<<<dim3((N + 63) / 64, 2), 256, 0, stream>>>(h0, h1, WT, BIAS, P, N);

  int egrid = (3 * E + 255) / 256;
  count_edges<<<egrid, 256, 0, stream>>>(d0, d1, d2, counts, E, N);

  int nchunks = (N + SCAN_CHUNK - 1) / SCAN_CHUNK;
  scan_partial<<<dim3(nchunks, 3), 256, 0, stream>>>(counts, offs, bsum, N);
  scan_bsums<<<3, 64, 0, stream>>>(bsum, nchunks);
  scan_add<<<dim3(nchunks, 3), 256, 0, stream>>>(offs, bsum, N);

  scatter_edges<<<egrid, 256, 0, stream>>>(d0, d1, d2, offs, cursor, elist, E, N);

  int fgrid = (N + 31) / 32;
  const ushort* K0 = P + (size_t)0 * N * 128;
  const ushort* K1 = P + (size_t)1 * N * 128;
  const ushort* V0 = P + (size_t)2 * N * 128;
  const ushort* V1 = P + (size_t)3 * N * 128;
  // dst type 0: relA=r0 (src t1: K1,V1, qt slot4, F slot7), relB=r2 (src t0: K0,V0, qt slot6, F slot9)
  agg_final<<<fgrid, 256, 0, stream>>>(
      elist + (size_t)0 * E, offs + (size_t)0 * (N + 1), s0, K1, V1,
      elist + (size_t)2 * E, offs + (size_t)2 * (N + 1), s2, K0, V0,
      2, 0, 2, 4, 6, 7, 9,
      WT, BIAS, h0, rel_pri, skip, 0, (float*)d_out, N);
  // dst type 1: relA=r1 (src t0: K0,V0, qt slot5, F slot8)
  agg_final<<<fgrid, 256, 0, stream>>>(
      elist + (size_t)1 * E, offs + (size_t)1 * (N + 1), s1, K0, V0,
      elist + (size_t)1 * E, offs + (size_t)1 * (N + 1), s1, K0, V0,
      1, 1, 1, 5, 5, 8, 8,
      WT, BIAS, h1, rel_pri, skip, 1, (float*)d_out + (size_t)N * 128, N);
}

// Round 12
// 360.052 us; speedup vs baseline: 1.2290x; 1.2290x over previous
//
#include <hip/hip_runtime.h>
#include <stdint.h>

typedef __attribute__((ext_vector_type(8))) short s16x8;
typedef __attribute__((ext_vector_type(4))) float f32x4;

__device__ __forceinline__ ushort f2bf(float x) {
  union { float f; uint32_t u; } v; v.f = x;
  uint32_t r = v.u + 0x7FFFu + ((v.u >> 16) & 1u);
  return (ushort)(r >> 16);
}
__device__ __forceinline__ float bf2f(ushort u) {
  union { uint32_t u; float f; } v; v.u = ((uint32_t)u) << 16; return v.f;
}

// Barrier that waits only LDS ops (lgkmcnt); global stores stay in flight.
__device__ __forceinline__ void barrier_lds_only() {
  asm volatile("s_waitcnt lgkmcnt(0)" ::: "memory");
  __builtin_amdgcn_s_barrier();
}

// ---------------------------------------------------------------------------
// Weight prep, 10 slots of transposed bf16 [col][k] + f32 bias.
//  0: kw0 raw  1: kw1 raw  2: vw0 raw  3: vw1 raw          (k/v projections)
//  4: qw0@BD(att0^T)  5: qw1@BD(att1^T)  6: qw0@BD(att2^T) (qt weights)
//  7: BD(msg0)@aw0    8: BD(msg1)@aw1    9: BD(msg2)@aw0   (folded output W)
// Identities: score=q·(k@att)=(q@att^T)·k ;  (Σw·v/Σw)@msg@aw = agg@(msg@aw)
// ---------------------------------------------------------------------------
__global__ __launch_bounds__(256) void prep_weights(
    const float* __restrict__ kw, const float* __restrict__ kb,
    const float* __restrict__ qw, const float* __restrict__ qb,
    const float* __restrict__ vw, const float* __restrict__ vb,
    const float* __restrict__ aw, const float* __restrict__ ab,
    const float* __restrict__ rel_att, const float* __restrict__ rel_msg,
    ushort* __restrict__ WT, float* __restrict__ BIAS)
{
  int slot = blockIdx.x, tid = threadIdx.x;
  const float* W; const float* b; const float* rel = nullptr; int mode;
  switch (slot) {
    case 0: W = kw;         b = kb;       mode = 0; break;
    case 1: W = kw + 16384; b = kb + 128; mode = 0; break;
    case 2: W = vw;         b = vb;       mode = 0; break;
    case 3: W = vw + 16384; b = vb + 128; mode = 0; break;
    case 4: W = qw;         b = qb;       rel = rel_att;        mode = 1; break;
    case 5: W = qw + 16384; b = qb + 128; rel = rel_att + 2048; mode = 1; break;
    case 6: W = qw;         b = qb;       rel = rel_att + 4096; mode = 1; break;
    case 7: W = aw;         b = ab;       rel = rel_msg;        mode = 2; break;
    case 8: W = aw + 16384; b = ab + 128; rel = rel_msg + 2048; mode = 2; break;
    default: W = aw;        b = ab;       rel = rel_msg + 4096; mode = 2; break;
  }
  ushort* out = WT + slot * 16384;
  for (int e = tid; e < 16384; e += 256) {
    int c = e >> 7, k = e & 127;
    float val;
    if (mode == 0) {
      val = W[k*128 + c];
    } else if (mode == 1) {           // qt: col c=(h,i): sum_j qw[:,h,j]*att[h,i,j]
      int h = c >> 4, cc = c & 15;
      float s = 0.f;
      #pragma unroll
      for (int j = 0; j < 16; j++) s += W[k*128 + h*16 + j] * rel[h*256 + cc*16 + j];
      val = s;
    } else {                          // F: row k=(h,i): sum_j msg[h,i,j]*aw[h*16+j, c]
      int hr = k >> 4, ir = k & 15;
      float s = 0.f;
      #pragma unroll
      for (int j = 0; j < 16; j++) s += rel[hr*256 + ir*16 + j] * W[(hr*16 + j)*128 + c];
      val = s;
    }
    out[c*128 + k] = f2bf(val);       // transposed [col][k]
  }
  if (tid < 128) {
    int c = tid; float val;
    if (mode == 1) {
      int h = c >> 4, cc = c & 15;
      float s = 0.f;
      #pragma unroll
      for (int j = 0; j < 16; j++) s += b[h*16 + j] * rel[h*256 + cc*16 + j];
      val = s;
    } else {
      val = b[c];                     // raw k/v bias, or ab for F slots
    }
    BIAS[slot*128 + c] = val;
  }
}

// ---------------------------------------------------------------------------
// Projection GEMM: 7 slots (k0,v0,qt_r0,qt_r2 from h0; k1,v1,qt_r1 from h1).
// Double-buffered LDS pipeline, nt copy-out.
//   blockIdx.y = 0 : A = h0, slots {0,2,4,6} (map 0x6420)
//   blockIdx.y = 1 : A = h1, slots {1,3,5}   (map 0x531)
// ---------------------------------------------------------------------------
__global__ __launch_bounds__(256) void proj_fused(
    const float* __restrict__ h0, const float* __restrict__ h1,
    const ushort* __restrict__ WT, const float* __restrict__ BIAS,
    ushort* __restrict__ P, int N)
{
  __shared__ ushort ALDS0[64 * 132];
  __shared__ ushort ALDS1[64 * 132];

  int src_t = blockIdx.y;
  const float* A = src_t ? h1 : h0;
  int nslots = src_t ? 3 : 4;
  unsigned smap = src_t ? 0x531u : 0x6420u;

  int tid = threadIdx.x;
  int lane = tid & 63;
  int wave = tid >> 6;
  int lr = lane & 15, lh = lane >> 4;
  int colbase = (wave & 1) * 64;
  int rowhalf = wave >> 1;

  int base = blockIdx.x * 64;
  if (base >= N) return;

  s16x8 af[2][4];
  #pragma unroll
  for (int rg = 0; rg < 2; rg++) {
    int arow = base + rowhalf*32 + rg*16 + lr;
    if (arow >= N) arow = N - 1;
    #pragma unroll
    for (int ks = 0; ks < 4; ks++) {
      const float* ap = A + (size_t)arow*128 + ks*32 + lh*8;
      f32x4 x0 = *(const f32x4*)ap;
      f32x4 x1 = *(const f32x4*)(ap + 4);
      s16x8 v;
      #pragma unroll
      for (int j = 0; j < 4; j++) { v[j] = (short)f2bf(x0[j]); v[4+j] = (short)f2bf(x1[j]); }
      af[rg][ks] = v;
    }
  }

  auto compute_slot = [&](int g, ushort* L) {
    const ushort* Bt = WT + g * 16384;
    const float* bias = BIAS + g * 128;
    #pragma unroll
    for (int ct = 0; ct < 4; ct++) {
      int col = colbase + ct*16 + lr;
      s16x8 bfr[4];
      #pragma unroll
      for (int ks = 0; ks < 4; ks++)
        bfr[ks] = *(const s16x8*)(Bt + col*128 + ks*32 + lh*8);
      float bb = bias[col];
      #pragma unroll
      for (int rg = 0; rg < 2; rg++) {
        f32x4 acc = { bb, bb, bb, bb };
        #pragma unroll
        for (int ks = 0; ks < 4; ks++)
          acc = __builtin_amdgcn_mfma_f32_16x16x32_bf16(af[rg][ks], bfr[ks], acc, 0, 0, 0);
        int rl0 = rowhalf*32 + rg*16 + lh*4;
        #pragma unroll
        for (int i = 0; i < 4; i++)
          L[(rl0 + i) * 132 + col] = f2bf(acc[i]);
      }
    }
  };

  auto copyout = [&](int g, const ushort* L) {
    ushort* C = P + (size_t)g * N * 128;
    #pragma unroll
    for (int j = 0; j < 4; j++) {
      int idx = j * 256 + tid;
      int row = idx >> 4, ch = idx & 15;
      int gr = base + row;
      if (gr < N)
        __builtin_nontemporal_store(
            *(const s16x8*)(L + row * 132 + ch * 8),
            (s16x8*)(C + (size_t)gr * 128 + ch * 8));
    }
  };

  int prev = smap & 15;
  compute_slot(prev, ALDS0);
  barrier_lds_only();
  for (int si = 1; si < nslots; si++) {
    int g = (smap >> (si * 4)) & 15;
    ushort* cur = (si & 1) ? ALDS1 : ALDS0;
    const ushort* pv = (si & 1) ? ALDS0 : ALDS1;
    copyout(prev, pv);
    compute_slot(g, cur);
    barrier_lds_only();
    prev = g;
  }
  copyout(prev, (nslots & 1) ? ALDS0 : ALDS1);
}

// ---------------------------------------------------------------------------
// CSR build
// ---------------------------------------------------------------------------
__global__ void count_edges(const int* __restrict__ d0, const int* __restrict__ d1,
                            const int* __restrict__ d2, int* __restrict__ counts,
                            int E, int N)
{
  int idx = blockIdx.x * 256 + threadIdx.x;
  if (idx >= 3 * E) return;
  int r = idx / E, e = idx - r * E;
  const int* D = (r == 0) ? d0 : (r == 1) ? d1 : d2;
  atomicAdd(counts + r * N + D[e], 1);
}

#define SCAN_CHUNK 2048
#define MAXC 1024

__global__ __launch_bounds__(256) void scan_partial(
    const int* __restrict__ counts, int* __restrict__ offsets,
    int* __restrict__ bsum, int N)
{
  int r = blockIdx.y, c = blockIdx.x, tid = threadIdx.x;
  const int* cnt = counts + (size_t)r * N;
  int* o = offsets + (size_t)r * (N + 1);
  int idx0 = c * SCAN_CHUNK + tid * 8;
  int p[8]; int run = 0;
  #pragma unroll
  for (int j = 0; j < 8; j++) {
    int v = (idx0 + j < N) ? cnt[idx0 + j] : 0;
    run += v; p[j] = run;
  }
  int lane = tid & 63, wid = tid >> 6;
  int x = run;
  #pragma unroll
  for (int off = 1; off < 64; off <<= 1) {
    int t = __shfl_up(x, off, 64);
    if (lane >= off) x += t;
  }
  __shared__ int wsum[4];
  if (lane == 63) wsum[wid] = x;
  __syncthreads();
  int woff = 0;
  for (int wph = 0; wph < wid; wph++) woff += wsum[wph];
  int texcl = woff + x - run;
  #pragma unroll
  for (int j = 0; j < 8; j++)
    if (idx0 + j < N) o[idx0 + j + 1] = texcl + p[j];
  if (tid == 255) bsum[r * MAXC + c] = woff + x;
}

__global__ void scan_bsums(int* __restrict__ bsum, int nchunks)
{
  int r = blockIdx.x, lane = threadIdx.x;
  int carry = 0;
  for (int base = 0; base < nchunks; base += 64) {
    int i = base + lane;
    int v0 = (i < nchunks) ? bsum[r * MAXC + i] : 0;
    int x = v0;
    #pragma unroll
    for (int off = 1; off < 64; off <<= 1) {
      int t = __shfl_up(x, off, 64);
      if (lane >= off) x += t;
    }
    if (i < nchunks) bsum[r * MAXC + i] = carry + x - v0;
    carry += __shfl(x, 63, 64);
  }
}

__global__ __launch_bounds__(256) void scan_add(
    int* __restrict__ offsets, const int* __restrict__ bsum, int N)
{
  int r = blockIdx.y, c = blockIdx.x, tid = threadIdx.x;
  int* o = offsets + (size_t)r * (N + 1);
  if (c == 0 && tid == 0) o[0] = 0;
  int add = bsum[r * MAXC + c];
  if (add == 0) return;
  int idx0 = c * SCAN_CHUNK + tid * 8;
  #pragma unroll
  for (int j = 0; j < 8; j++) {
    int i = idx0 + j;
    if (i < N) o[i + 1] += add;
  }
}

// Scatter stores the SRC node id directly (removes one dependent random load
// per edge in the aggregation loop).
__global__ void scatter_edges(const int* __restrict__ d0, const int* __restrict__ d1,
                              const int* __restrict__ d2,
                              const int* __restrict__ s0, const int* __restrict__ s1,
                              const int* __restrict__ s2,
                              const int* __restrict__ offsets, int* __restrict__ cursor,
                              int* __restrict__ slist, int E, int N)
{
  int idx = blockIdx.x * 256 + threadIdx.x;
  if (idx >= 3 * E) return;
  int r = idx / E, e = idx - r * E;
  const int* D = (r == 0) ? d0 : (r == 1) ? d1 : d2;
  const int* S = (r == 0) ? s0 : (r == 1) ? s1 : s2;
  int dst = D[e];
  int pos = offsets[r * (N + 1) + dst] + atomicAdd(cursor + r * N + dst, 1);
  slist[r * E + pos] = S[e];
}

// ---------------------------------------------------------------------------
// Merged fused attention + output for BOTH dst types (grid.y: 0=t0, 1=t1).
// Per (dst,h): qt row read coalesced from precomputed slot; single-pass edge
// loop with 2-deep software pipeline (prefetch next src + its K/V rows while
// computing current); no max-subtraction (|score|<~8, f32-safe). Phase 2:
// agg @ folded F_r (MFMA), mean, +ab, skip-mix, nt store.
// Block = 256 threads = 32 dst x 8 heads.
// ---------------------------------------------------------------------------
__global__ __launch_bounds__(256) void agg_final(
    const int* __restrict__ slist, const int* __restrict__ offs,
    const ushort* __restrict__ P,
    const ushort* __restrict__ WT, const float* __restrict__ BIAS,
    const float* __restrict__ h0, const float* __restrict__ h1,
    const float* __restrict__ rel_pri, const float* __restrict__ skip,
    float* __restrict__ out, int N, int E)
{
  __shared__ ushort T0[32 * 132];
  __shared__ ushort T1[32 * 132];

  int ty = blockIdx.y;
  int tid = threadIdx.x;
  int dstl = tid >> 3, h = tid & 7;
  int base = blockIdx.x * 32;
  int dst = base + dstl;
  bool valid = dst < N;
  const float* H = ty ? h1 : h0;
  float* outT = out + (size_t)ty * N * 128;

  const ushort* K0 = P;
  const ushort* K1 = P + (size_t)1 * N * 128;
  const ushort* V0 = P + (size_t)2 * N * 128;
  const ushort* V1 = P + (size_t)3 * N * 128;

  // ---- relation A: r0 (t0, src t1) or r1 (t1, src t0) ----
  {
    int rA = ty ? 1 : 0;
    const int* sl = slist + (size_t)rA * E;
    const int* of = offs + (size_t)rA * (N + 1);
    const ushort* K = ty ? K0 : K1;
    const ushort* V = ty ? V0 : V1;
    const ushort* QT = P + (size_t)(ty ? 5 : 4) * N * 128;

    float qf[16];
    const ushort* qr = QT + (size_t)(valid ? dst : 0) * 128 + h * 16;
    #pragma unroll
    for (int j = 0; j < 16; j++) qf[j] = bf2f(qr[j]);
    float pr = rel_pri[rA * 8 + h] * 0.25f;

    float acc[16];
    #pragma unroll
    for (int j = 0; j < 16; j++) acc[j] = 0.f;
    float sum = 0.f;
    int b0 = valid ? of[dst] : 0, b1 = valid ? of[dst + 1] : 0;
    if (b1 > b0) {
      int scur = sl[b0];
      const ushort* kr = K + (size_t)scur * 128 + h * 16;
      const ushort* vr = V + (size_t)scur * 128 + h * 16;
      s16x8 k0 = *(const s16x8*)kr, k1 = *(const s16x8*)(kr + 8);
      s16x8 v0 = *(const s16x8*)vr, v1 = *(const s16x8*)(vr + 8);
      for (int i = b0; i < b1; i++) {
        int snx = (i + 1 < b1) ? sl[i + 1] : scur;
        const ushort* krn = K + (size_t)snx * 128 + h * 16;
        const ushort* vrn = V + (size_t)snx * 128 + h * 16;
        s16x8 k0n = *(const s16x8*)krn, k1n = *(const s16x8*)(krn + 8);
        s16x8 v0n = *(const s16x8*)vrn, v1n = *(const s16x8*)(vrn + 8);
        float sc = 0.f;
        #pragma unroll
        for (int j = 0; j < 8; j++)
          sc += qf[j] * bf2f((ushort)k0[j]) + qf[8+j] * bf2f((ushort)k1[j]);
        float w = __expf(sc * pr);
        #pragma unroll
        for (int j = 0; j < 8; j++) {
          acc[j]   += w * bf2f((ushort)v0[j]);
          acc[8+j] += w * bf2f((ushort)v1[j]);
        }
        sum += w;
        k0 = k0n; k1 = k1n; v0 = v0n; v1 = v1n;
      }
    }
    float inv = (b1 > b0) ? 1.0f / sum : 0.f;
    ushort* a0 = T0 + dstl * 132 + h * 16;
    #pragma unroll
    for (int j = 0; j < 16; j++) a0[j] = f2bf(acc[j] * inv);
  }

  // ---- relation B: r2 (t0 only, src t0) ----
  if (ty == 0) {
    const int* sl = slist + (size_t)2 * E;
    const int* of = offs + (size_t)2 * (N + 1);
    const ushort* K = K0;
    const ushort* V = V0;
    const ushort* QT = P + (size_t)6 * N * 128;

    float qf[16];
    const ushort* qr = QT + (size_t)(valid ? dst : 0) * 128 + h * 16;
    #pragma unroll
    for (int j = 0; j < 16; j++) qf[j] = bf2f(qr[j]);
    float pr = rel_pri[2 * 8 + h] * 0.25f;

    float acc[16];
    #pragma unroll
    for (int j = 0; j < 16; j++) acc[j] = 0.f;
    float sum = 0.f;
    int b0 = valid ? of[dst] : 0, b1 = valid ? of[dst + 1] : 0;
    if (b1 > b0) {
      int scur = sl[b0];
      const ushort* kr = K + (size_t)scur * 128 + h * 16;
      const ushort* vr = V + (size_t)scur * 128 + h * 16;
      s16x8 k0 = *(const s16x8*)kr, k1 = *(const s16x8*)(kr + 8);
      s16x8 v0 = *(const s16x8*)vr, v1 = *(const s16x8*)(vr + 8);
      for (int i = b0; i < b1; i++) {
        int snx = (i + 1 < b1) ? sl[i + 1] : scur;
        const ushort* krn = K + (size_t)snx * 128 + h * 16;
        const ushort* vrn = V + (size_t)snx * 128 + h * 16;
        s16x8 k0n = *(const s16x8*)krn, k1n = *(const s16x8*)(krn + 8);
        s16x8 v0n = *(const s16x8*)vrn, v1n = *(const s16x8*)(vrn + 8);
        float sc = 0.f;
        #pragma unroll
        for (int j = 0; j < 8; j++)
          sc += qf[j] * bf2f((ushort)k0[j]) + qf[8+j] * bf2f((ushort)k1[j]);
        float w = __expf(sc * pr);
        #pragma unroll
        for (int j = 0; j < 8; j++) {
          acc[j]   += w * bf2f((ushort)v0[j]);
          acc[8+j] += w * bf2f((ushort)v1[j]);
        }
        sum += w;
        k0 = k0n; k1 = k1n; v0 = v0n; v1 = v1n;
      }
    }
    float inv = (b1 > b0) ? 1.0f / sum : 0.f;
    ushort* a1 = T1 + dstl * 132 + h * 16;
    #pragma unroll
    for (int j = 0; j < 16; j++) a1[j] = f2bf(acc[j] * inv);
  }
  __syncthreads();

  // ---- phase 2: output GEMM with folded F_r, mean, +ab, skip-mix ----
  int lane = tid & 63, wv = tid >> 6;
  int lr = lane & 15, lh = lane >> 4;
  int rowhalf = wv & 1, colhalf = wv >> 1;
  int fA = ty ? 8 : 7;
  const float* bias = BIAS + fA * 128;            // ab[t]
  float alpha = 1.0f / (1.0f + __expf(-skip[ty]));
  float beta = 1.0f - alpha;
  float rscale = ty ? 1.0f : 0.5f;

  s16x8 afA[4], afB[4];
  int arow_l = rowhalf * 16 + lr;
  #pragma unroll
  for (int ks = 0; ks < 4; ks++)
    afA[ks] = *(const s16x8*)(T0 + arow_l * 132 + ks * 32 + lh * 8);
  if (ty == 0) {
    #pragma unroll
    for (int ks = 0; ks < 4; ks++)
      afB[ks] = *(const s16x8*)(T1 + arow_l * 132 + ks * 32 + lh * 8);
  }

  #pragma unroll
  for (int ct = 0; ct < 4; ct++) {
    int col = colhalf * 64 + ct * 16 + lr;
    const ushort* BtA = WT + fA * 16384;
    s16x8 bfrA[4];
    #pragma unroll
    for (int ks = 0; ks < 4; ks++)
      bfrA[ks] = *(const s16x8*)(BtA + col * 128 + ks * 32 + lh * 8);
    f32x4 acc = { 0.f, 0.f, 0.f, 0.f };
    #pragma unroll
    for (int ks = 0; ks < 4; ks++)
      acc = __builtin_amdgcn_mfma_f32_16x16x32_bf16(afA[ks], bfrA[ks], acc, 0, 0, 0);
    if (ty == 0) {
      const ushort* BtB = WT + 9 * 16384;
      s16x8 bfrB[4];
      #pragma unroll
      for (int ks = 0; ks < 4; ks++)
        bfrB[ks] = *(const s16x8*)(BtB + col * 128 + ks * 32 + lh * 8);
      #pragma unroll
      for (int ks = 0; ks < 4; ks++)
        acc = __builtin_amdgcn_mfma_f32_16x16x32_bf16(afB[ks], bfrB[ks], acc, 0, 0, 0);
    }
    float bb = bias[col];
    int r0l = rowhalf * 16 + lh * 4;
    #pragma unroll
    for (int i = 0; i < 4; i++) {
      int g = base + r0l + i;
      if (g < N) {
        size_t off = (size_t)g * 128 + col;
        __builtin_nontemporal_store((acc[i] * rscale + bb) * alpha + H[off] * beta,
                                    &outT[off]);
      }
    }
  }
}

// ---------------------------------------------------------------------------
extern "C" void kernel_launch(void* const* d_in, const int* in_sizes, int n_in,
                              void* d_out, int out_size, void* d_ws, size_t ws_size,
                              hipStream_t stream)
{
  const float* h0      = (const float*)d_in[0];
  const float* h1      = (const float*)d_in[1];
  const float* kw      = (const float*)d_in[2];
  const float* kb      = (const float*)d_in[3];
  const float* qw      = (const float*)d_in[4];
  const float* qb      = (const float*)d_in[5];
  const float* vw      = (const float*)d_in[6];
  const float* vb      = (const float*)d_in[7];
  const float* aw      = (const float*)d_in[8];
  const float* ab      = (const float*)d_in[9];
  const float* rel_att = (const float*)d_in[10];
  const float* rel_msg = (const float*)d_in[11];
  const float* rel_pri = (const float*)d_in[12];
  const float* skip    = (const float*)d_in[13];
  const int* s0 = (const int*)d_in[14];
  const int* d0 = (const int*)d_in[15];
  const int* s1 = (const int*)d_in[16];
  const int* d1 = (const int*)d_in[17];
  const int* s2 = (const int*)d_in[18];
  const int* d2 = (const int*)d_in[19];

  int N = in_sizes[0] / 128;
  int E = in_sizes[14];

  char* w = (char*)d_ws;
  size_t o = 0;
  auto alloc = [&](size_t bytes) { size_t cur = o; o += (bytes + 255) / 256 * 256; return cur; };
  ushort* WT   = (ushort*)(w + alloc((size_t)10 * 16384 * 2));
  float*  BIAS = (float*) (w + alloc((size_t)10 * 128 * 4));
  ushort* P    = (ushort*)(w + alloc((size_t)7 * N * 128 * 2));
  int* counts  = (int*)   (w + alloc((size_t)3 * N * 4));
  int* cursor  = (int*)   (w + alloc((size_t)3 * N * 4));
  int* offs    = (int*)   (w + alloc((size_t)3 * (N + 1) * 4));
  int* slist   = (int*)   (w + alloc((size_t)3 * E * 4));
  int* bsum    = (int*)   (w + alloc((size_t)3 * MAXC * 4));
  (void)ws_size; (void)n_in; (void)out_size;

  hipMemsetAsync(counts, 0, (size_t)3 * N * 4, stream);
  hipMemsetAsync(cursor, 0, (size_t)3 * N * 4, stream);

  prep_weights<<<10, 256, 0, stream>>>(kw, kb, qw, qb, vw, vb, aw, ab,
                                       rel_att, rel_msg, WT, BIAS);

  proj_fused<<<dim3((N + 63) / 64, 2), 256, 0, stream>>>(h0, h1, WT, BIAS, P, N);

  int egrid = (3 * E + 255) / 256;
  count_edges<<<egrid, 256, 0, stream>>>(d0, d1, d2, counts, E, N);

  int nchunks = (N + SCAN_CHUNK - 1) / SCAN_CHUNK;
  scan_partial<<<dim3(nchunks, 3), 256, 0, stream>>>(counts, offs, bsum, N);
  scan_bsums<<<3, 64, 0, stream>>>(bsum, nchunks);
  scan_add<<<dim3(nchunks, 3), 256, 0, stream>>>(offs, bsum, N);

  scatter_edges<<<egrid, 256, 0, stream>>>(d0, d1, d2, s0, s1, s2,
                                           offs, cursor, slist, E, N);

  int fgrid = (N + 31) / 32;
  agg_final<<<dim3(fgrid, 2), 256, 0, stream>>>(
      slist, offs, P, WT, BIAS, h0, h1, rel_pri, skip,
      (float*)d_out, N, E);
}